// Round 10
// baseline (161.611 us; speedup 1.0000x reference)
//
#include <hip/hip_runtime.h>
#include <stdint.h>

typedef __bf16 bf16_t;
typedef bf16_t bf16x8 __attribute__((ext_vector_type(8)));
typedef short bf16x4s __attribute__((ext_vector_type(4)));
typedef float f32x4 __attribute__((ext_vector_type(4)));

static __device__ __forceinline__ unsigned short f2bf(float f) {
    union { float f; unsigned int u; } v; v.f = f;
    unsigned int u = v.u;
    unsigned int r = (u + 0x7fffu + ((u >> 16) & 1u)) >> 16;
    return (unsigned short)r;
}

static __device__ __forceinline__ bf16x8 as_frag(uint4 v) {
    union { uint4 u; bf16x8 b; } c; c.u = v; return c.b;
}
static __device__ __forceinline__ bf16x4s as_frag4(uint2 v) {
    union { uint2 u; bf16x4s b; } c; c.u = v; return c.b;
}

static __device__ __forceinline__ unsigned int fbits(float f) {
    union { float f; unsigned int u; } v; v.f = f; return v.u;
}
static __device__ __forceinline__ float fval(unsigned int u) {
    union { unsigned int u; float f; } v; v.u = u; return v.f;
}

// async global->LDS, 16B per lane. LDS dst must be wave-uniform base + lane*16.
static __device__ __forceinline__ void gl2lds16(const unsigned short* g, uint4* l) {
    __builtin_amdgcn_global_load_lds(
        (const __attribute__((address_space(1))) unsigned int*)g,
        (__attribute__((address_space(3))) unsigned int*)l, 16, 0, 0);
}

#define MFMA16(a, b, c) __builtin_amdgcn_mfma_f32_16x16x32_bf16((a), (b), (c), 0, 0, 0)

// 16x16x16 bf16 MFMA (K=16): A-operand layout k=quad*4+j matches S^T C-layout
// keys exactly -> P never touches LDS. Name guarded (CDNA2 carried-forward).
#if __has_builtin(__builtin_amdgcn_mfma_f32_16x16x16bf16_1k)
#define MFMA_PV(a, b, c) __builtin_amdgcn_mfma_f32_16x16x16bf16_1k((a), (b), (c), 0, 0, 0)
#define HAVE_PV16 1
#elif __has_builtin(__builtin_amdgcn_mfma_f32_16x16x16_bf16)
#define MFMA_PV(a, b, c) __builtin_amdgcn_mfma_f32_16x16x16_bf16((a), (b), (c), 0, 0, 0)
#define HAVE_PV16 1
#else
#define HAVE_PV16 0
#endif

// softmax scale folded into Q at gemm1 epilogue: 0.125 * log2(e)
#define QSCALE 0.1803368801111204f

// ---------------------------------------------------------------------------
// fp32 -> bf16 convert, all three tensors in one launch (y selects tensor)
// ---------------------------------------------------------------------------
__global__ void cvt_all(const float* __restrict__ x,
                        const float* __restrict__ wq,
                        const float* __restrict__ wo,
                        unsigned short* __restrict__ xb,
                        unsigned short* __restrict__ wqb,
                        unsigned short* __restrict__ wob) {
    const float* in; unsigned short* out; int n4;
    if (blockIdx.y == 0)      { in = x;  out = xb;  n4 = 1048576; }
    else if (blockIdx.y == 1) { in = wq; out = wqb; n4 = 786432; }
    else                      { in = wo; out = wob; n4 = 262144; }
    for (int i = blockIdx.x * 256 + threadIdx.x; i < n4; i += 1024 * 256) {
        float4 v = ((const float4*)in)[i];
        ushort4 o;
        o.x = f2bf(v.x); o.y = f2bf(v.y); o.z = f2bf(v.z); o.w = f2bf(v.w);
        ((ushort4*)out)[i] = o;
    }
}

// ---------------------------------------------------------------------------
// C[M,N] = A[M,K] * B[N,K]^T  (K-major bf16), BMx128 tile, BK=64.
// launch_bounds(256,2): 64 AGPR acc + ~164 VGPR must fit the UNIFIED gfx950
// register file — a 3-waves/EU cap (~170) forces accumulator spills (R6 bug).
// ---------------------------------------------------------------------------
template <int OUTMODE, int BM>
__global__ __launch_bounds__(256, 2) void gemm_bt(
    const unsigned short* __restrict__ A,
    const unsigned short* __restrict__ B,
    void* __restrict__ Cv,
    const float* __restrict__ bias,
    unsigned short* __restrict__ Vt,
    int M, int N, int K) {
    constexpr int MT = BM / 32;
    __shared__ uint4 As[BM * 8];
    __shared__ uint4 Bs[1024];
    const int tid  = threadIdx.x;
    const int lane = tid & 63;
    const int wave = tid >> 6;
    const int quad = lane >> 4;
    const int l16  = lane & 15;
    const int wr   = (wave >> 1) * (BM / 2);
    const int wc   = (wave & 1) * 64;
    const int bm   = blockIdx.y * BM;
    const int bn   = blockIdx.x * 128;

    f32x4 zero4 = {0.f, 0.f, 0.f, 0.f};
    f32x4 acc[MT][4];
#pragma unroll
    for (int mt = 0; mt < MT; ++mt)
#pragma unroll
        for (int nt = 0; nt < 4; ++nt) acc[mt][nt] = zero4;

    const int s_row = tid >> 3;
    const int s_kcs = tid & 7;

    for (int k0 = 0; k0 < K; k0 += 64) {
        __syncthreads();
#pragma unroll
        for (int i = 0; i < MT; ++i) {
            int row = i * 32 + s_row;
            int kcg = s_kcs ^ (row & 7);
            gl2lds16(A + (size_t)(bm + row) * K + k0 + kcg * 8, &As[i * 256 + tid]);
        }
#pragma unroll
        for (int i = 0; i < 4; ++i) {
            int row = i * 32 + s_row;
            int kcg = s_kcs ^ (row & 7);
            gl2lds16(B + (size_t)(bn + row) * K + k0 + kcg * 8, &Bs[i * 256 + tid]);
        }
        __syncthreads();
#pragma unroll
        for (int ks = 0; ks < 2; ++ks) {
            int kc = ks * 4 + quad;
            bf16x8 af[MT], bff[4];
#pragma unroll
            for (int mt = 0; mt < MT; ++mt) {
                int row = wr + mt * 16 + l16;
                af[mt] = as_frag(As[row * 8 + (kc ^ (row & 7))]);
            }
#pragma unroll
            for (int nt = 0; nt < 4; ++nt) {
                int row = wc + nt * 16 + l16;
                bff[nt] = as_frag(Bs[row * 8 + (kc ^ (row & 7))]);
            }
#pragma unroll
            for (int mt = 0; mt < MT; ++mt)
#pragma unroll
                for (int nt = 0; nt < 4; ++nt)
                    acc[mt][nt] = MFMA16(af[mt], bff[nt], acc[mt][nt]);
        }
    }

    if (OUTMODE == 1) {
        float* C = (float*)Cv;
#pragma unroll
        for (int mt = 0; mt < MT; ++mt)
#pragma unroll
            for (int nt = 0; nt < 4; ++nt) {
                int col = bn + wc + nt * 16 + l16;
                float bv = bias ? bias[col] : 0.f;
#pragma unroll
                for (int r = 0; r < 4; ++r) {
                    int row = bm + wr + mt * 16 + quad * 4 + r;
                    C[(size_t)row * N + col] = acc[mt][nt][r] + bv;
                }
            }
    } else if (OUTMODE == 0) {
        unsigned short* C = (unsigned short*)Cv;
#pragma unroll
        for (int mt = 0; mt < MT; ++mt)
#pragma unroll
            for (int nt = 0; nt < 4; ++nt) {
                int col = bn + wc + nt * 16 + l16;
#pragma unroll
                for (int r = 0; r < 4; ++r) {
                    int row = bm + wr + mt * 16 + quad * 4 + r;
                    C[(size_t)row * N + col] = f2bf(acc[mt][nt][r]);
                }
            }
    } else {
        if (bn < 2048) {
            unsigned short* C = (unsigned short*)Cv;  // [4096, 2048] Q|K
#pragma unroll
            for (int mt = 0; mt < MT; ++mt)
#pragma unroll
                for (int nt = 0; nt < 4; ++nt) {
                    int col = bn + wc + nt * 16 + l16;
                    float sc = (col < 1024) ? QSCALE : 1.0f;  // pre-scale Q
#pragma unroll
                    for (int r = 0; r < 4; ++r) {
                        int row = bm + wr + mt * 16 + quad * 4 + r;
                        C[(size_t)row * 2048 + col] = f2bf(acc[mt][nt][r] * sc);
                    }
                }
        } else {
            // V part: write transposed Vt[(b*16+h)*64 + dd][token]
#pragma unroll
            for (int mt = 0; mt < MT; ++mt)
#pragma unroll
                for (int nt = 0; nt < 4; ++nt) {
                    int col = bn + wc + nt * 16 + l16 - 2048;
                    int h = col >> 6, dd = col & 63;
                    int token0 = bm + wr + mt * 16 + quad * 4;
                    int b = token0 >> 10, t = token0 & 1023;
                    ushort4 pk;
                    pk.x = f2bf(acc[mt][nt][0]);
                    pk.y = f2bf(acc[mt][nt][1]);
                    pk.z = f2bf(acc[mt][nt][2]);
                    pk.w = f2bf(acc[mt][nt][3]);
                    *(ushort4*)(Vt + ((size_t)((b * 16 + h) * 64 + dd) * 1024 + t)) = pk;
                }
        }
    }
}

// ---------------------------------------------------------------------------
// Flash attention, no-max softmax (Q pre-scaled by QSCALE). (unchanged R9)
// Block = (bh, 128-q-tile): 256 threads = 4 waves; wave owns 32 q (2 subs).
// QK^T via 16x16x32; PV via 16x16x16 with P entirely in registers.
// ---------------------------------------------------------------------------
__global__ __launch_bounds__(256, 3) void attn_kernel(
    const unsigned short* __restrict__ qk,
    const unsigned short* __restrict__ vt,
    unsigned short* __restrict__ out) {
    __shared__ uint4 Ps[1024];     // 16KB: Q-stage (P fallback buffer if needed)
    __shared__ uint4 Ks[2][512];   // 16KB: 64 keys x 64 d
    __shared__ uint4 Vs[2][512];   // 16KB: 64 dd x 64 tok

    const int tid  = threadIdx.x;
    const int lane = tid & 63;
    const int wave = tid >> 6;        // 0..3
    const int quad = lane >> 4;
    const int l16  = lane & 15;
    const int bh   = blockIdx.x;      // 0..63
    const int b    = bh >> 4, h = bh & 15;
    const int qbase = blockIdx.y * 128;
    const size_t rowbase = (size_t)b * 1024;
    const int hoff = h * 64;

    const int st_row = tid >> 3;      // 0..31 (pass adds 32)
    const int st_c   = tid & 7;
    const unsigned short* kp0 = qk + rowbase * 2048 + 1024 + hoff;
    const unsigned short* vp0 = vt + (size_t)bh * 65536;

    // ---- prologue: issue K0/V0 + Q loads ----
#pragma unroll
    for (int p = 0; p < 2; ++p) {
        int row = p * 32 + st_row;
        int cg = st_c ^ (row & 7);
        gl2lds16(kp0 + (size_t)row * 2048 + cg * 8, &Ks[0][p * 256 + tid]);
        gl2lds16(vp0 + (size_t)row * 1024 + cg * 8, &Vs[0][p * 256 + tid]);
    }
#pragma unroll
    for (int p = 0; p < 4; ++p) {
        int row = p * 32 + st_row;
        int cg = st_c ^ (row & 7);
        gl2lds16(qk + (rowbase + qbase + row) * 2048 + hoff + cg * 8,
                 &Ps[p * 256 + tid]);
    }
    __syncthreads();

    bf16x8 qf[2][2];
#pragma unroll
    for (int sub = 0; sub < 2; ++sub)
#pragma unroll
        for (int ks = 0; ks < 2; ++ks) {
            int kc = ks * 4 + quad;
            int row = wave * 32 + sub * 16 + l16;
            qf[sub][ks] = as_frag(Ps[row * 8 + (kc ^ (row & 7))]);
        }

    f32x4 zero4 = {0.f, 0.f, 0.f, 0.f};
    f32x4 Oacc[2][4];
#pragma unroll
    for (int sub = 0; sub < 2; ++sub)
#pragma unroll
        for (int no = 0; no < 4; ++no) Oacc[sub][no] = zero4;
    float lsum[2] = {0.f, 0.f};

#if !HAVE_PV16
    uint4* const Pw = Ps + wave * 256;
#endif

    for (int kt = 0; kt < 16; ++kt) {
        const int buf = kt & 1;
        if (kt) __syncthreads();
        if (kt < 15) {
#pragma unroll
            for (int p = 0; p < 2; ++p) {
                int row = p * 32 + st_row;
                int cg = st_c ^ (row & 7);
                gl2lds16(kp0 + (size_t)((kt + 1) * 64 + row) * 2048 + cg * 8,
                         &Ks[buf ^ 1][p * 256 + tid]);
                gl2lds16(vp0 + (size_t)row * 1024 + (kt + 1) * 64 + cg * 8,
                         &Vs[buf ^ 1][p * 256 + tid]);
            }
        }

        // ---- S^T = K * Q^T : lane holds [key=quad*4+r][q=l16] ----
        f32x4 st[2][4];
#pragma unroll
        for (int sub = 0; sub < 2; ++sub)
#pragma unroll
            for (int nt = 0; nt < 4; ++nt) st[sub][nt] = zero4;
#pragma unroll
        for (int ks = 0; ks < 2; ++ks) {
            int kc = ks * 4 + quad;
#pragma unroll
            for (int nt = 0; nt < 4; ++nt) {
                int row = nt * 16 + l16;
                bf16x8 kf = as_frag(Ks[buf][row * 8 + (kc ^ (row & 7))]);
                st[0][nt] = MFMA16(kf, qf[0][ks], st[0][nt]);
                st[1][nt] = MFMA16(kf, qf[1][ks], st[1][nt]);
            }
        }

        // ---- softmax (no max): exp2, truncate, pack to A-frags in regs ----
        uint2 pA[2][4];
#pragma unroll
        for (int sub = 0; sub < 2; ++sub) {
            float rs = 0.f;
#pragma unroll
            for (int nt = 0; nt < 4; ++nt) {
                unsigned int b0 = fbits(__builtin_amdgcn_exp2f(st[sub][nt][0])) & 0xffff0000u;
                unsigned int b1 = fbits(__builtin_amdgcn_exp2f(st[sub][nt][1])) & 0xffff0000u;
                unsigned int b2 = fbits(__builtin_amdgcn_exp2f(st[sub][nt][2])) & 0xffff0000u;
                unsigned int b3 = fbits(__builtin_amdgcn_exp2f(st[sub][nt][3])) & 0xffff0000u;
                rs += (fval(b0) + fval(b1)) + (fval(b2) + fval(b3));
                pA[sub][nt].x = __builtin_amdgcn_perm(b1, b0, 0x07060302u);
                pA[sub][nt].y = __builtin_amdgcn_perm(b3, b2, 0x07060302u);
            }
            lsum[sub] += rs;
        }

#if HAVE_PV16
        // ---- O += P * V, P in registers (16x16x16: A k=quad*4+j == S^T keys)
        {
            const uint2* v64 = (const uint2*)Vs[buf];
#pragma unroll
            for (int s = 0; s < 4; ++s) {
                int kc = s * 2 + (quad >> 1);       // 16B tok-chunk 0..7
                bf16x4s pa0 = as_frag4(pA[0][s]);
                bf16x4s pa1 = as_frag4(pA[1][s]);
#pragma unroll
                for (int no = 0; no < 4; ++no) {
                    int dd = no * 16 + l16;
                    bf16x4s vb = as_frag4(v64[(dd * 8 + (kc ^ (dd & 7))) * 2 + (quad & 1)]);
                    Oacc[0][no] = MFMA_PV(pa0, vb, Oacc[0][no]);
                    Oacc[1][no] = MFMA_PV(pa1, vb, Oacc[1][no]);
                }
            }
        }
#else
        // ---- fallback: P via wave-private LDS (R6 path) ----
#pragma unroll
        for (int sub = 0; sub < 2; ++sub) {
            int row = sub * 16 + l16;
#pragma unroll
            for (int nt = 0; nt < 4; ++nt) {
                int kc = nt * 2 + (quad >> 1);
                ((uint2*)Pw)[(row * 8 + (kc ^ (row & 7))) * 2 + (quad & 1)] =
                    make_uint2(pA[sub][nt].x, pA[sub][nt].y);
            }
        }
#pragma unroll
        for (int k2 = 0; k2 < 2; ++k2) {
            int kc = k2 * 4 + quad;
            bf16x8 pf[2];
#pragma unroll
            for (int sub = 0; sub < 2; ++sub) {
                int row = sub * 16 + l16;
                pf[sub] = as_frag(Pw[row * 8 + (kc ^ (row & 7))]);
            }
#pragma unroll
            for (int no = 0; no < 4; ++no) {
                int dd = no * 16 + l16;
                bf16x8 vf = as_frag(Vs[buf][dd * 8 + (kc ^ (dd & 7))]);
                Oacc[0][no] = MFMA16(pf[0], vf, Oacc[0][no]);
                Oacc[1][no] = MFMA16(pf[1], vf, Oacc[1][no]);
            }
        }
#endif
    }

    // ---- epilogue: reduce l across quads, normalize, store ----
#pragma unroll
    for (int sub = 0; sub < 2; ++sub) {
        lsum[sub] += __shfl_xor(lsum[sub], 16, 64);
        lsum[sub] += __shfl_xor(lsum[sub], 32, 64);
        float linv = 1.f / lsum[sub];
#pragma unroll
        for (int r = 0; r < 4; ++r) {
            float iv = __shfl(linv, quad * 4 + r, 64);
            int qrow = qbase + wave * 32 + sub * 16 + quad * 4 + r;
#pragma unroll
            for (int no = 0; no < 4; ++no) {
                int dd = no * 16 + l16;
                out[(rowbase + qrow) * 1024 + hoff + dd] = f2bf(Oacc[sub][no][r] * iv);
            }
        }
    }
}

// ---------------------------------------------------------------------------
extern "C" void kernel_launch(void* const* d_in, const int* in_sizes, int n_in,
                              void* d_out, int out_size, void* d_ws, size_t ws_size,
                              hipStream_t stream) {
    const float* x     = (const float*)d_in[0];  // [4,1024,1024]
    const float* w_qkv = (const float*)d_in[1];  // [3072,1024]
    const float* w_out = (const float*)d_in[2];  // [1024,1024]
    const float* b_out = (const float*)d_in[3];  // [1024]

    char* ws = (char*)d_ws;
    unsigned short* wqkvb = (unsigned short*)(ws);              // 6 MB
    unsigned short* woutb = (unsigned short*)(ws + 6291456);    // 2 MB
    unsigned short* qkb   = (unsigned short*)(ws + 8388608);    // 16 MB [4096,2048]
    unsigned short* vtb   = (unsigned short*)(ws + 25165824);   // 8 MB  [64,64,1024]
    unsigned short* xb    = (unsigned short*)(ws + 33554432);   // 8 MB  [4096,1024]
    unsigned short* attnb = xb;  // xb dead after gemm1 (stream-ordered)

    cvt_all<<<dim3(1024, 3), 256, 0, stream>>>(x, w_qkv, w_out, xb, wqkvb, woutb);

    // qkv = x @ w_qkv^T : Q (pre-scaled) |K -> qkb, V -> vtb transposed
    gemm_bt<2, 128><<<dim3(24, 32), 256, 0, stream>>>(xb, wqkvb, (void*)qkb,
                                                      nullptr, vtb, 4096, 3072, 1024);
    // attention -> [4096,1024] bf16 (grid x=bh for XCD L2 locality)
    attn_kernel<<<dim3(64, 8), 256, 0, stream>>>(qkb, vtb, attnb);
    // out = attn @ w_out^T + b : fp32, BM=64 -> 512 blocks = 2/CU
    gemm_bt<1, 64><<<dim3(8, 64), 256, 0, stream>>>(attnb, woutb, d_out, b_out,
                                                    nullptr, 4096, 1024, 1024);
}

// Round 11
// 159.456 us; speedup vs baseline: 1.0135x; 1.0135x over previous
//
#include <hip/hip_runtime.h>
#include <stdint.h>

typedef __bf16 bf16_t;
typedef bf16_t bf16x8 __attribute__((ext_vector_type(8)));
typedef short bf16x4s __attribute__((ext_vector_type(4)));
typedef float f32x4 __attribute__((ext_vector_type(4)));

static __device__ __forceinline__ unsigned short f2bf(float f) {
    union { float f; unsigned int u; } v; v.f = f;
    unsigned int u = v.u;
    unsigned int r = (u + 0x7fffu + ((u >> 16) & 1u)) >> 16;
    return (unsigned short)r;
}

static __device__ __forceinline__ bf16x8 as_frag(uint4 v) {
    union { uint4 u; bf16x8 b; } c; c.u = v; return c.b;
}
static __device__ __forceinline__ bf16x4s as_frag4(uint2 v) {
    union { uint2 u; bf16x4s b; } c; c.u = v; return c.b;
}

static __device__ __forceinline__ unsigned int fbits(float f) {
    union { float f; unsigned int u; } v; v.f = f; return v.u;
}
static __device__ __forceinline__ float fval(unsigned int u) {
    union { unsigned int u; float f; } v; v.u = u; return v.f;
}

// async global->LDS, 16B per lane. LDS dst must be wave-uniform base + lane*16.
static __device__ __forceinline__ void gl2lds16(const unsigned short* g, uint4* l) {
    __builtin_amdgcn_global_load_lds(
        (const __attribute__((address_space(1))) unsigned int*)g,
        (__attribute__((address_space(3))) unsigned int*)l, 16, 0, 0);
}

#define MFMA16(a, b, c) __builtin_amdgcn_mfma_f32_16x16x32_bf16((a), (b), (c), 0, 0, 0)

// 16x16x16 bf16 MFMA (K=16): A-operand layout k=quad*4+j matches S^T C-layout
// keys exactly -> P never touches LDS. Name guarded (CDNA2 carried-forward).
#if __has_builtin(__builtin_amdgcn_mfma_f32_16x16x16bf16_1k)
#define MFMA_PV(a, b, c) __builtin_amdgcn_mfma_f32_16x16x16bf16_1k((a), (b), (c), 0, 0, 0)
#define HAVE_PV16 1
#elif __has_builtin(__builtin_amdgcn_mfma_f32_16x16x16_bf16)
#define MFMA_PV(a, b, c) __builtin_amdgcn_mfma_f32_16x16x16_bf16((a), (b), (c), 0, 0, 0)
#define HAVE_PV16 1
#else
#define HAVE_PV16 0
#endif

// softmax scale folded into Q at gemm1 epilogue: 0.125 * log2(e)
#define QSCALE 0.1803368801111204f

// ---------------------------------------------------------------------------
// fp32 -> bf16 convert, all three tensors in one launch (y selects tensor)
// ---------------------------------------------------------------------------
__global__ void cvt_all(const float* __restrict__ x,
                        const float* __restrict__ wq,
                        const float* __restrict__ wo,
                        unsigned short* __restrict__ xb,
                        unsigned short* __restrict__ wqb,
                        unsigned short* __restrict__ wob) {
    const float* in; unsigned short* out; int n4;
    if (blockIdx.y == 0)      { in = x;  out = xb;  n4 = 1048576; }
    else if (blockIdx.y == 1) { in = wq; out = wqb; n4 = 786432; }
    else                      { in = wo; out = wob; n4 = 262144; }
    for (int i = blockIdx.x * 256 + threadIdx.x; i < n4; i += 1024 * 256) {
        float4 v = ((const float4*)in)[i];
        ushort4 o;
        o.x = f2bf(v.x); o.y = f2bf(v.y); o.z = f2bf(v.z); o.w = f2bf(v.w);
        ((ushort4*)out)[i] = o;
    }
}

// ---------------------------------------------------------------------------
// C[M,N] = A[M,K] * B[N,K]^T  (K-major bf16), BMx128 tile, BK=64.
// (256,3) is the MEASURED best (R9 156.6 vs R10's (256,2) 161.6).
// OUTMODE 2 V-path: coalesced transpose through LDS (As reused, stride 136).
// ---------------------------------------------------------------------------
template <int OUTMODE, int BM>
__global__ __launch_bounds__(256, 3) void gemm_bt(
    const unsigned short* __restrict__ A,
    const unsigned short* __restrict__ B,
    void* __restrict__ Cv,
    const float* __restrict__ bias,
    unsigned short* __restrict__ Vt,
    int M, int N, int K) {
    constexpr int MT = BM / 32;
    // OUTMODE 2 needs 64x136 ushort (1088 uint4) for the V transpose staging
    constexpr int ASZ = (OUTMODE == 2 && BM * 8 < 1088) ? 1088 : BM * 8;
    __shared__ uint4 As[ASZ];
    __shared__ uint4 Bs[1024];
    const int tid  = threadIdx.x;
    const int lane = tid & 63;
    const int wave = tid >> 6;
    const int quad = lane >> 4;
    const int l16  = lane & 15;
    const int wr   = (wave >> 1) * (BM / 2);
    const int wc   = (wave & 1) * 64;
    const int bm   = blockIdx.y * BM;
    const int bn   = blockIdx.x * 128;

    f32x4 zero4 = {0.f, 0.f, 0.f, 0.f};
    f32x4 acc[MT][4];
#pragma unroll
    for (int mt = 0; mt < MT; ++mt)
#pragma unroll
        for (int nt = 0; nt < 4; ++nt) acc[mt][nt] = zero4;

    const int s_row = tid >> 3;
    const int s_kcs = tid & 7;

    for (int k0 = 0; k0 < K; k0 += 64) {
        __syncthreads();
#pragma unroll
        for (int i = 0; i < MT; ++i) {
            int row = i * 32 + s_row;
            int kcg = s_kcs ^ (row & 7);
            gl2lds16(A + (size_t)(bm + row) * K + k0 + kcg * 8, &As[i * 256 + tid]);
        }
#pragma unroll
        for (int i = 0; i < 4; ++i) {
            int row = i * 32 + s_row;
            int kcg = s_kcs ^ (row & 7);
            gl2lds16(B + (size_t)(bn + row) * K + k0 + kcg * 8, &Bs[i * 256 + tid]);
        }
        __syncthreads();
#pragma unroll
        for (int ks = 0; ks < 2; ++ks) {
            int kc = ks * 4 + quad;
            bf16x8 af[MT], bff[4];
#pragma unroll
            for (int mt = 0; mt < MT; ++mt) {
                int row = wr + mt * 16 + l16;
                af[mt] = as_frag(As[row * 8 + (kc ^ (row & 7))]);
            }
#pragma unroll
            for (int nt = 0; nt < 4; ++nt) {
                int row = wc + nt * 16 + l16;
                bff[nt] = as_frag(Bs[row * 8 + (kc ^ (row & 7))]);
            }
#pragma unroll
            for (int mt = 0; mt < MT; ++mt)
#pragma unroll
                for (int nt = 0; nt < 4; ++nt)
                    acc[mt][nt] = MFMA16(af[mt], bff[nt], acc[mt][nt]);
        }
    }

    if (OUTMODE == 1) {
        float* C = (float*)Cv;
#pragma unroll
        for (int mt = 0; mt < MT; ++mt)
#pragma unroll
            for (int nt = 0; nt < 4; ++nt) {
                int col = bn + wc + nt * 16 + l16;
                float bv = bias ? bias[col] : 0.f;
#pragma unroll
                for (int r = 0; r < 4; ++r) {
                    int row = bm + wr + mt * 16 + quad * 4 + r;
                    C[(size_t)row * N + col] = acc[mt][nt][r] + bv;
                }
            }
    } else if (OUTMODE == 0) {
        unsigned short* C = (unsigned short*)Cv;
#pragma unroll
        for (int mt = 0; mt < MT; ++mt)
#pragma unroll
            for (int nt = 0; nt < 4; ++nt) {
                int col = bn + wc + nt * 16 + l16;
#pragma unroll
                for (int r = 0; r < 4; ++r) {
                    int row = bm + wr + mt * 16 + quad * 4 + r;
                    C[(size_t)row * N + col] = f2bf(acc[mt][nt][r]);
                }
            }
    } else {
        if (bn < 2048) {
            unsigned short* C = (unsigned short*)Cv;  // [4096, 2048] Q|K
#pragma unroll
            for (int mt = 0; mt < MT; ++mt)
#pragma unroll
                for (int nt = 0; nt < 4; ++nt) {
                    int col = bn + wc + nt * 16 + l16;
                    float sc = (col < 1024) ? QSCALE : 1.0f;  // pre-scale Q
#pragma unroll
                    for (int r = 0; r < 4; ++r) {
                        int row = bm + wr + mt * 16 + quad * 4 + r;
                        C[(size_t)row * 2048 + col] = f2bf(acc[mt][nt][r] * sc);
                    }
                }
        } else {
            // V: coalesced transpose via LDS. Block covers heads h0,h0+1
            // (dd 0..63 each), tokens [bm, bm+128). Waves with (wave&1)==hh
            // own head hh's columns (wc selects the 64-col half).
            unsigned short* Ts = (unsigned short*)As;  // 64 x 136 ushort
            const int b0   = bm >> 10;
            const int tloc = bm & 1023;
            const int h0   = (bn - 2048) >> 6;
            const int dd_r = tid >> 2;            // reader row 0..63
            const int ch_r = (tid & 3) * 32;      // reader tok chunk
#pragma unroll
            for (int hh = 0; hh < 2; ++hh) {
                __syncthreads();
                if ((wave & 1) == hh) {
#pragma unroll
                    for (int mt = 0; mt < MT; ++mt)
#pragma unroll
                        for (int nt = 0; nt < 4; ++nt) {
                            int dd  = nt * 16 + l16;
                            int tok = wr + mt * 16 + quad * 4;
#pragma unroll
                            for (int r = 0; r < 4; ++r)
                                Ts[dd * 136 + tok + r] = f2bf(acc[mt][nt][r]);
                        }
                }
                __syncthreads();
                unsigned short* dst = Vt +
                    ((size_t)((b0 * 16 + h0 + hh) * 64 + dd_r) * 1024 + tloc + ch_r);
#pragma unroll
                for (int k = 0; k < 4; ++k) {
                    uint4 v = *(const uint4*)(Ts + dd_r * 136 + ch_r + k * 8);
                    *(uint4*)(dst + k * 8) = v;
                }
            }
        }
    }
}

// ---------------------------------------------------------------------------
// Flash attention, no-max softmax (Q pre-scaled by QSCALE). (unchanged R9)
// Block = (bh, 128-q-tile): 256 threads = 4 waves; wave owns 32 q (2 subs).
// QK^T via 16x16x32; PV via 16x16x16 with P entirely in registers.
// ---------------------------------------------------------------------------
__global__ __launch_bounds__(256, 3) void attn_kernel(
    const unsigned short* __restrict__ qk,
    const unsigned short* __restrict__ vt,
    unsigned short* __restrict__ out) {
    __shared__ uint4 Ps[1024];     // 16KB: Q-stage (P fallback buffer if needed)
    __shared__ uint4 Ks[2][512];   // 16KB: 64 keys x 64 d
    __shared__ uint4 Vs[2][512];   // 16KB: 64 dd x 64 tok

    const int tid  = threadIdx.x;
    const int lane = tid & 63;
    const int wave = tid >> 6;        // 0..3
    const int quad = lane >> 4;
    const int l16  = lane & 15;
    const int bh   = blockIdx.x;      // 0..63
    const int b    = bh >> 4, h = bh & 15;
    const int qbase = blockIdx.y * 128;
    const size_t rowbase = (size_t)b * 1024;
    const int hoff = h * 64;

    const int st_row = tid >> 3;      // 0..31 (pass adds 32)
    const int st_c   = tid & 7;
    const unsigned short* kp0 = qk + rowbase * 2048 + 1024 + hoff;
    const unsigned short* vp0 = vt + (size_t)bh * 65536;

    // ---- prologue: issue K0/V0 + Q loads ----
#pragma unroll
    for (int p = 0; p < 2; ++p) {
        int row = p * 32 + st_row;
        int cg = st_c ^ (row & 7);
        gl2lds16(kp0 + (size_t)row * 2048 + cg * 8, &Ks[0][p * 256 + tid]);
        gl2lds16(vp0 + (size_t)row * 1024 + cg * 8, &Vs[0][p * 256 + tid]);
    }
#pragma unroll
    for (int p = 0; p < 4; ++p) {
        int row = p * 32 + st_row;
        int cg = st_c ^ (row & 7);
        gl2lds16(qk + (rowbase + qbase + row) * 2048 + hoff + cg * 8,
                 &Ps[p * 256 + tid]);
    }
    __syncthreads();

    bf16x8 qf[2][2];
#pragma unroll
    for (int sub = 0; sub < 2; ++sub)
#pragma unroll
        for (int ks = 0; ks < 2; ++ks) {
            int kc = ks * 4 + quad;
            int row = wave * 32 + sub * 16 + l16;
            qf[sub][ks] = as_frag(Ps[row * 8 + (kc ^ (row & 7))]);
        }

    f32x4 zero4 = {0.f, 0.f, 0.f, 0.f};
    f32x4 Oacc[2][4];
#pragma unroll
    for (int sub = 0; sub < 2; ++sub)
#pragma unroll
        for (int no = 0; no < 4; ++no) Oacc[sub][no] = zero4;
    float lsum[2] = {0.f, 0.f};

#if !HAVE_PV16
    uint4* const Pw = Ps + wave * 256;
#endif

    for (int kt = 0; kt < 16; ++kt) {
        const int buf = kt & 1;
        if (kt) __syncthreads();
        if (kt < 15) {
#pragma unroll
            for (int p = 0; p < 2; ++p) {
                int row = p * 32 + st_row;
                int cg = st_c ^ (row & 7);
                gl2lds16(kp0 + (size_t)((kt + 1) * 64 + row) * 2048 + cg * 8,
                         &Ks[buf ^ 1][p * 256 + tid]);
                gl2lds16(vp0 + (size_t)row * 1024 + (kt + 1) * 64 + cg * 8,
                         &Vs[buf ^ 1][p * 256 + tid]);
            }
        }

        // ---- S^T = K * Q^T : lane holds [key=quad*4+r][q=l16] ----
        f32x4 st[2][4];
#pragma unroll
        for (int sub = 0; sub < 2; ++sub)
#pragma unroll
            for (int nt = 0; nt < 4; ++nt) st[sub][nt] = zero4;
#pragma unroll
        for (int ks = 0; ks < 2; ++ks) {
            int kc = ks * 4 + quad;
#pragma unroll
            for (int nt = 0; nt < 4; ++nt) {
                int row = nt * 16 + l16;
                bf16x8 kf = as_frag(Ks[buf][row * 8 + (kc ^ (row & 7))]);
                st[0][nt] = MFMA16(kf, qf[0][ks], st[0][nt]);
                st[1][nt] = MFMA16(kf, qf[1][ks], st[1][nt]);
            }
        }

        // ---- softmax (no max): exp2, truncate, pack to A-frags in regs ----
        uint2 pA[2][4];
#pragma unroll
        for (int sub = 0; sub < 2; ++sub) {
            float rs = 0.f;
#pragma unroll
            for (int nt = 0; nt < 4; ++nt) {
                unsigned int b0 = fbits(__builtin_amdgcn_exp2f(st[sub][nt][0])) & 0xffff0000u;
                unsigned int b1 = fbits(__builtin_amdgcn_exp2f(st[sub][nt][1])) & 0xffff0000u;
                unsigned int b2 = fbits(__builtin_amdgcn_exp2f(st[sub][nt][2])) & 0xffff0000u;
                unsigned int b3 = fbits(__builtin_amdgcn_exp2f(st[sub][nt][3])) & 0xffff0000u;
                rs += (fval(b0) + fval(b1)) + (fval(b2) + fval(b3));
                pA[sub][nt].x = __builtin_amdgcn_perm(b1, b0, 0x07060302u);
                pA[sub][nt].y = __builtin_amdgcn_perm(b3, b2, 0x07060302u);
            }
            lsum[sub] += rs;
        }

#if HAVE_PV16
        // ---- O += P * V, P in registers (16x16x16: A k=quad*4+j == S^T keys)
        {
            const uint2* v64 = (const uint2*)Vs[buf];
#pragma unroll
            for (int s = 0; s < 4; ++s) {
                int kc = s * 2 + (quad >> 1);       // 16B tok-chunk 0..7
                bf16x4s pa0 = as_frag4(pA[0][s]);
                bf16x4s pa1 = as_frag4(pA[1][s]);
#pragma unroll
                for (int no = 0; no < 4; ++no) {
                    int dd = no * 16 + l16;
                    bf16x4s vb = as_frag4(v64[(dd * 8 + (kc ^ (dd & 7))) * 2 + (quad & 1)]);
                    Oacc[0][no] = MFMA_PV(pa0, vb, Oacc[0][no]);
                    Oacc[1][no] = MFMA_PV(pa1, vb, Oacc[1][no]);
                }
            }
        }
#else
        // ---- fallback: P via wave-private LDS (R6 path) ----
#pragma unroll
        for (int sub = 0; sub < 2; ++sub) {
            int row = sub * 16 + l16;
#pragma unroll
            for (int nt = 0; nt < 4; ++nt) {
                int kc = nt * 2 + (quad >> 1);
                ((uint2*)Pw)[(row * 8 + (kc ^ (row & 7))) * 2 + (quad & 1)] =
                    make_uint2(pA[sub][nt].x, pA[sub][nt].y);
            }
        }
#pragma unroll
        for (int k2 = 0; k2 < 2; ++k2) {
            int kc = k2 * 4 + quad;
            bf16x8 pf[2];
#pragma unroll
            for (int sub = 0; sub < 2; ++sub) {
                int row = sub * 16 + l16;
                pf[sub] = as_frag(Pw[row * 8 + (kc ^ (row & 7))]);
            }
#pragma unroll
            for (int no = 0; no < 4; ++no) {
                int dd = no * 16 + l16;
                bf16x8 vf = as_frag(Vs[buf][dd * 8 + (kc ^ (dd & 7))]);
                Oacc[0][no] = MFMA16(pf[0], vf, Oacc[0][no]);
                Oacc[1][no] = MFMA16(pf[1], vf, Oacc[1][no]);
            }
        }
#endif
    }

    // ---- epilogue: reduce l across quads, normalize, store ----
#pragma unroll
    for (int sub = 0; sub < 2; ++sub) {
        lsum[sub] += __shfl_xor(lsum[sub], 16, 64);
        lsum[sub] += __shfl_xor(lsum[sub], 32, 64);
        float linv = 1.f / lsum[sub];
#pragma unroll
        for (int r = 0; r < 4; ++r) {
            float iv = __shfl(linv, quad * 4 + r, 64);
            int qrow = qbase + wave * 32 + sub * 16 + quad * 4 + r;
#pragma unroll
            for (int no = 0; no < 4; ++no) {
                int dd = no * 16 + l16;
                out[(rowbase + qrow) * 1024 + hoff + dd] = f2bf(Oacc[sub][no][r] * iv);
            }
        }
    }
}

// ---------------------------------------------------------------------------
extern "C" void kernel_launch(void* const* d_in, const int* in_sizes, int n_in,
                              void* d_out, int out_size, void* d_ws, size_t ws_size,
                              hipStream_t stream) {
    const float* x     = (const float*)d_in[0];  // [4,1024,1024]
    const float* w_qkv = (const float*)d_in[1];  // [3072,1024]
    const float* w_out = (const float*)d_in[2];  // [1024,1024]
    const float* b_out = (const float*)d_in[3];  // [1024]

    char* ws = (char*)d_ws;
    unsigned short* wqkvb = (unsigned short*)(ws);              // 6 MB
    unsigned short* woutb = (unsigned short*)(ws + 6291456);    // 2 MB
    unsigned short* qkb   = (unsigned short*)(ws + 8388608);    // 16 MB [4096,2048]
    unsigned short* vtb   = (unsigned short*)(ws + 25165824);   // 8 MB  [64,64,1024]
    unsigned short* xb    = (unsigned short*)(ws + 33554432);   // 8 MB  [4096,1024]
    unsigned short* attnb = xb;  // xb dead after gemm1 (stream-ordered)

    cvt_all<<<dim3(1024, 3), 256, 0, stream>>>(x, w_qkv, w_out, xb, wqkvb, woutb);

    // qkv = x @ w_qkv^T : Q (pre-scaled) |K -> qkb, V -> vtb transposed
    gemm_bt<2, 128><<<dim3(24, 32), 256, 0, stream>>>(xb, wqkvb, (void*)qkb,
                                                      nullptr, vtb, 4096, 3072, 1024);
    // attention -> [4096,1024] bf16 (grid x=bh for XCD L2 locality)
    attn_kernel<<<dim3(64, 8), 256, 0, stream>>>(qkb, vtb, attnb);
    // out = attn @ w_out^T + b : fp32, BM=64 -> 512 blocks = 2/CU
    gemm_bt<1, 64><<<dim3(8, 64), 256, 0, stream>>>(attnb, woutb, d_out, b_out,
                                                    nullptr, 4096, 1024, 1024);
}